// Round 1
// baseline (1541.974 us; speedup 1.0000x reference)
//
#include <hip/hip_runtime.h>
#include <math.h>

#define FDIM 64
#define CATDIM 192

// ---------------- degree / normalization ----------------

__global__ void k_deg_init(float* deg, int n3) {
    int i = blockIdx.x * blockDim.x + threadIdx.x;
    if (i < n3) deg[i] = 1.0f;   // self-loop contributes weight 1
}

__global__ void k_deg_acc(const int* __restrict__ ei0,
                          const int* __restrict__ ei1,
                          const int* __restrict__ ei2,
                          const float* __restrict__ w1,
                          const float* __restrict__ w2,
                          float* __restrict__ deg0,
                          float* __restrict__ deg1,
                          float* __restrict__ deg2,
                          int E) {
    int e = blockIdx.x * blockDim.x + threadIdx.x;
    if (e >= E) return;
    atomicAdd(&deg0[ei0[E + e]], 1.0f);
    atomicAdd(&deg1[ei1[E + e]], w1[e]);
    atomicAdd(&deg2[ei2[E + e]], w2[e]);
}

__global__ void k_dis(float* d, int n3) {
    int i = blockIdx.x * blockDim.x + threadIdx.x;
    if (i < n3) {
        float v = d[i];
        d[i] = v > 0.f ? rsqrtf(v) : 0.f;
    }
}

// ---------------- small GEMM: out[n][64] = A[n][K] * W[64][K]^T ----------------
// 16 nodes per block, 256 threads: lane f = tid&63 computes feature f for
// 4 nodes (q = tid>>6 selects which 4). W transposed into LDS with +1 pad
// (bank = (k+f)%32 -> 2-way, free). A rows staged contiguously in LDS.

__global__ __launch_bounds__(256) void k_gemm_nt(const float* __restrict__ A,
                                                 const float* __restrict__ W,
                                                 float* __restrict__ out,
                                                 int n, int K) {
    __shared__ float wt[192 * 65];   // [k][f] padded
    __shared__ float xs[16 * 192];   // [node_local][k] contiguous

    const int tid = threadIdx.x;
    const int n0 = blockIdx.x * 16;

    for (int t = tid; t < FDIM * K; t += 256) {
        int f = t / K;
        int k = t - f * K;
        wt[k * 65 + f] = W[t];
    }
    for (int t = tid; t < 16 * K; t += 256) {
        int node = n0 + t / K;
        xs[t] = (node < n) ? A[(size_t)n0 * K + t] : 0.f;
    }
    __syncthreads();

    const int f = tid & 63;
    const int q = tid >> 6;
    float acc[4] = {0.f, 0.f, 0.f, 0.f};

    for (int k = 0; k < K; k += 4) {
        float w0 = wt[(k + 0) * 65 + f];
        float w1 = wt[(k + 1) * 65 + f];
        float w2 = wt[(k + 2) * 65 + f];
        float w3 = wt[(k + 3) * 65 + f];
#pragma unroll
        for (int j = 0; j < 4; ++j) {
            const float4 xv = *reinterpret_cast<const float4*>(&xs[(q * 4 + j) * K + k]);
            acc[j] = fmaf(xv.x, w0, fmaf(xv.y, w1, fmaf(xv.z, w2, fmaf(xv.w, w3, acc[j]))));
        }
    }

#pragma unroll
    for (int j = 0; j < 4; ++j) {
        int node = n0 + q * 4 + j;
        if (node < n) out[(size_t)node * FDIM + f] = acc[j];
    }
}

// ---------------- dgconv: self-loop init + edge scatter ----------------

__global__ void k_selfinit(const float* __restrict__ h,
                           const float* __restrict__ dis,   // [3][N]
                           float* __restrict__ cat, int n) {
    int idx = blockIdx.x * blockDim.x + threadIdx.x;
    if (idx >= n * FDIM) return;
    int i = idx >> 6;
    int f = idx & 63;
    float hv = h[idx];
    float d0 = dis[i];
    float d1 = dis[n + i];
    float d2 = dis[2 * n + i];
    size_t base = (size_t)i * CATDIM + f;
    cat[base]       = d0 * d0 * hv;
    cat[base + 64]  = d1 * d1 * hv;
    cat[base + 128] = d2 * d2 * hv;
}

// one 64-lane group per edge; lane = feature
__global__ __launch_bounds__(256) void k_scatter(const int* __restrict__ ei,   // [2][E]
                                                 const float* __restrict__ w,  // may be null
                                                 const float* __restrict__ dis,
                                                 const float* __restrict__ h,
                                                 float* __restrict__ cat,
                                                 int E, int goff) {
    int t = blockIdx.x * 4 + (threadIdx.x >> 6);
    if (t >= E) return;
    int lane = threadIdx.x & 63;
    int row = ei[t];
    int col = ei[E + t];
    float wv = w ? w[t] : 1.0f;
    float norm = dis[row] * wv * dis[col];
    float val = norm * h[(size_t)row * FDIM + lane];
    atomicAdd(&cat[(size_t)col * CATDIM + goff + lane], val);
}

__global__ void k_biasrelu(float* __restrict__ cat, const float* __restrict__ bias, int n) {
    int idx = blockIdx.x * blockDim.x + threadIdx.x;
    if (idx >= n * CATDIM) return;
    int c = idx % CATDIM;
    float v = cat[idx] + bias[c & 63];
    cat[idx] = v > 0.f ? v : 0.f;
}

// ---------------- final: pointwise conv (16 out) + log_softmax ----------------
// block = 256 = 16 nodes x 16 outputs. conv_w in LDS padded to 196.

__global__ __launch_bounds__(256) void k_final(const float* __restrict__ cat,
                                               const float* __restrict__ convw,  // [16][192]
                                               const float* __restrict__ convb,  // [16]
                                               float* __restrict__ out, int n) {
    __shared__ float wl[16 * 196];
    __shared__ float bl[16];
    const int tid = threadIdx.x;
    for (int t = tid; t < 16 * 192; t += 256) {
        int o = t / 192;
        int k = t - o * 192;
        wl[o * 196 + k] = convw[t];
    }
    if (tid < 16) bl[tid] = convb[tid];
    __syncthreads();

    const int o = tid & 15;
    const int node = blockIdx.x * 16 + (tid >> 4);
    const int nc = node < n ? node : n - 1;

    const float4* xr = reinterpret_cast<const float4*>(cat + (size_t)nc * CATDIM);
    const float* wr = &wl[o * 196];
    float acc = bl[o];
#pragma unroll
    for (int k4 = 0; k4 < CATDIM / 4; ++k4) {
        float4 xv = xr[k4];
        acc += xv.x * wr[k4 * 4 + 0] + xv.y * wr[k4 * 4 + 1] +
               xv.z * wr[k4 * 4 + 2] + xv.w * wr[k4 * 4 + 3];
    }

    // log_softmax across the 16 lanes sharing a node (lane groups are 16-aligned)
    float m = acc;
    m = fmaxf(m, __shfl_xor(m, 1));
    m = fmaxf(m, __shfl_xor(m, 2));
    m = fmaxf(m, __shfl_xor(m, 4));
    m = fmaxf(m, __shfl_xor(m, 8));
    float s = __expf(acc - m);
    s += __shfl_xor(s, 1);
    s += __shfl_xor(s, 2);
    s += __shfl_xor(s, 4);
    s += __shfl_xor(s, 8);
    if (node < n) out[(size_t)node * 16 + o] = acc - m - logf(s);
}

// ---------------- launch ----------------

extern "C" void kernel_launch(void* const* d_in, const int* in_sizes, int n_in,
                              void* d_out, int out_size, void* d_ws, size_t ws_size,
                              hipStream_t stream) {
    const float* x      = (const float*)d_in[0];
    const int*   ei     = (const int*)d_in[1];
    const int*   e_in   = (const int*)d_in[2];
    const int*   e_out  = (const int*)d_in[3];
    const float* in_w   = (const float*)d_in[4];
    const float* out_w  = (const float*)d_in[5];
    const float* lin1_w = (const float*)d_in[6];
    const float* lin2_w = (const float*)d_in[7];
    const float* bias1  = (const float*)d_in[8];
    const float* bias2  = (const float*)d_in[9];
    const float* conv_w = (const float*)d_in[10];
    const float* conv_b = (const float*)d_in[11];
    float* out = (float*)d_out;

    const int N = in_sizes[0] / 128;
    const int E = in_sizes[1] / 2;

    float* ws  = (float*)d_ws;
    float* dis = ws;                         // 3N  (holds deg first, then dis)
    float* h   = dis + (size_t)3 * N;        // N*64
    float* cat = h + (size_t)N * FDIM;       // N*192

    const int B = 256;

    // normalization factors (shared by both layers)
    hipLaunchKernelGGL(k_deg_init, dim3((3 * N + B - 1) / B), dim3(B), 0, stream, dis, 3 * N);
    hipLaunchKernelGGL(k_deg_acc, dim3((E + B - 1) / B), dim3(B), 0, stream,
                       ei, e_in, e_out, in_w, out_w, dis, dis + N, dis + 2 * N, E);
    hipLaunchKernelGGL(k_dis, dim3((3 * N + B - 1) / B), dim3(B), 0, stream, dis, 3 * N);

    // layer 1
    hipLaunchKernelGGL(k_gemm_nt, dim3((N + 15) / 16), dim3(B), 0, stream, x, lin1_w, h, N, 128);
    hipLaunchKernelGGL(k_selfinit, dim3((N * FDIM + B - 1) / B), dim3(B), 0, stream, h, dis, cat, N);
    hipLaunchKernelGGL(k_scatter, dim3((E + 3) / 4), dim3(B), 0, stream, ei,    (const float*)nullptr, dis,         h, cat, E, 0);
    hipLaunchKernelGGL(k_scatter, dim3((E + 3) / 4), dim3(B), 0, stream, e_in,  in_w,                  dis + N,     h, cat, E, 64);
    hipLaunchKernelGGL(k_scatter, dim3((E + 3) / 4), dim3(B), 0, stream, e_out, out_w,                 dis + 2 * N, h, cat, E, 128);
    hipLaunchKernelGGL(k_biasrelu, dim3((N * CATDIM + B - 1) / B), dim3(B), 0, stream, cat, bias1, N);

    // layer 2
    hipLaunchKernelGGL(k_gemm_nt, dim3((N + 15) / 16), dim3(B), 0, stream, cat, lin2_w, h, N, 192);
    hipLaunchKernelGGL(k_selfinit, dim3((N * FDIM + B - 1) / B), dim3(B), 0, stream, h, dis, cat, N);
    hipLaunchKernelGGL(k_scatter, dim3((E + 3) / 4), dim3(B), 0, stream, ei,    (const float*)nullptr, dis,         h, cat, E, 0);
    hipLaunchKernelGGL(k_scatter, dim3((E + 3) / 4), dim3(B), 0, stream, e_in,  in_w,                  dis + N,     h, cat, E, 64);
    hipLaunchKernelGGL(k_scatter, dim3((E + 3) / 4), dim3(B), 0, stream, e_out, out_w,                 dis + 2 * N, h, cat, E, 128);
    hipLaunchKernelGGL(k_biasrelu, dim3((N * CATDIM + B - 1) / B), dim3(B), 0, stream, cat, bias2, N);

    // head
    hipLaunchKernelGGL(k_final, dim3((N + 15) / 16), dim3(B), 0, stream, cat, conv_w, conv_b, out, N);
}

// Round 2
// 814.591 us; speedup vs baseline: 1.8929x; 1.8929x over previous
//
#include <hip/hip_runtime.h>
#include <math.h>

#define FDIM 64
#define CATDIM 192

// ============ init: deg = 1 (self-loop), cnt = 0 ============

__global__ void k_init(float* __restrict__ deg, int* __restrict__ cnt, int n3) {
    int i = blockIdx.x * blockDim.x + threadIdx.x;
    if (i < n3) { deg[i] = 1.0f; cnt[i] = 0; }
}

// ============ edge pass 1: degree (float) + histogram (int), all 3 graphs ============

__global__ void k_edge_pass1(const int* __restrict__ ei0,
                             const int* __restrict__ ei1,
                             const int* __restrict__ ei2,
                             const float* __restrict__ w1,
                             const float* __restrict__ w2,
                             float* __restrict__ deg,   // [3][N]
                             int* __restrict__ cnt,     // [3][N]
                             int N, int E) {
    int e = blockIdx.x * blockDim.x + threadIdx.x;
    if (e >= E) return;
    int c0 = ei0[E + e];
    int c1 = ei1[E + e];
    int c2 = ei2[E + e];
    atomicAdd(&deg[c0], 1.0f);
    atomicAdd(&deg[N + c1], w1[e]);
    atomicAdd(&deg[2 * N + c2], w2[e]);
    atomicAdd(&cnt[c0], 1);
    atomicAdd(&cnt[N + c1], 1);
    atomicAdd(&cnt[2 * N + c2], 1);
}

__global__ void k_dis(float* d, int n3) {
    int i = blockIdx.x * blockDim.x + threadIdx.x;
    if (i < n3) {
        float v = d[i];
        d[i] = v > 0.f ? rsqrtf(v) : 0.f;
    }
}

// ============ hierarchical exclusive scan of cnt -> rowptr, cursor ============

__global__ void k_scan1(const int* __restrict__ cnt, int* __restrict__ bsum,
                        int N, int nblk) {
    __shared__ int r[256];
    int g = blockIdx.y, b = blockIdx.x, tid = threadIdx.x;
    int i = b * 256 + tid;
    int v = (i < N) ? cnt[g * N + i] : 0;
    r[tid] = v;
    __syncthreads();
    for (int d = 128; d > 0; d >>= 1) {
        if (tid < d) r[tid] += r[tid + d];
        __syncthreads();
    }
    if (tid == 0) bsum[g * nblk + b] = r[0];
}

__global__ void k_scan2(int* bsum, int nblk) {
    __shared__ int s[256];
    int g = blockIdx.x, tid = threadIdx.x;
    int v = (tid < nblk) ? bsum[g * nblk + tid] : 0;
    s[tid] = v;
    __syncthreads();
    for (int d = 1; d < 256; d <<= 1) {
        int t = (tid >= d) ? s[tid - d] : 0;
        __syncthreads();
        s[tid] += t;
        __syncthreads();
    }
    if (tid < nblk) bsum[g * nblk + tid] = s[tid] - v;   // exclusive
}

__global__ void k_scan3(const int* __restrict__ cnt, const int* __restrict__ bsum,
                        int* __restrict__ rowptr, int* __restrict__ cursor,
                        int N, int nblk) {
    __shared__ int s[256];
    int g = blockIdx.y, b = blockIdx.x, tid = threadIdx.x;
    int i = b * 256 + tid;
    int v = (i < N) ? cnt[g * N + i] : 0;
    s[tid] = v;
    __syncthreads();
    for (int d = 1; d < 256; d <<= 1) {
        int t = (tid >= d) ? s[tid - d] : 0;
        __syncthreads();
        s[tid] += t;
        __syncthreads();
    }
    if (i <= N) {
        int e = bsum[g * nblk + b] + (s[tid] - v);
        rowptr[g * (N + 1) + i] = e;
        cursor[g * (N + 1) + i] = e;
    }
}

// ============ edge pass 2: fill CSR (src node + premultiplied w*dis[row]) ============

__global__ void k_fill(const int* __restrict__ ei0,
                       const int* __restrict__ ei1,
                       const int* __restrict__ ei2,
                       const float* __restrict__ w1,
                       const float* __restrict__ w2,
                       const float* __restrict__ dis,   // [3][N]
                       int* __restrict__ cursor,        // [3][N+1]
                       int* __restrict__ src,           // [3][E]
                       float* __restrict__ val,         // [3][E]
                       int N, int E) {
    int e = blockIdx.x * blockDim.x + threadIdx.x;
    if (e >= E) return;
    {
        int r = ei0[e], c = ei0[E + e];
        int slot = atomicAdd(&cursor[c], 1);
        src[slot] = r;
        val[slot] = dis[r];                    // w = 1
    }
    {
        int r = ei1[e], c = ei1[E + e];
        int slot = atomicAdd(&cursor[(N + 1) + c], 1);
        src[E + slot] = r;
        val[E + slot] = w1[e] * dis[N + r];
    }
    {
        int r = ei2[e], c = ei2[E + e];
        int slot = atomicAdd(&cursor[2 * (N + 1) + c], 1);
        src[2 * E + slot] = r;
        val[2 * E + slot] = w2[e] * dis[2 * N + r];
    }
}

// ============ GEMM: out[n][64] = A[n][K] * W[64][K]^T ============
// 64 nodes/block, 256 threads. W transposed in LDS wt[k][65] (+1 pad, conflict
// free both staging and reads). A staged per 32-wide K chunk: xs[node][36]
// (b128-aligned, group-q nodes interleaved mod 4 -> distinct banks).
// Thread (f=tid&63, q=tid>>6) accumulates 16 nodes j = jj*4+q.

template <int K>
__global__ __launch_bounds__(256) void k_gemm(const float* __restrict__ A,
                                              const float* __restrict__ W,
                                              float* __restrict__ out, int n) {
    __shared__ float wt[K * 65];
    __shared__ float xs[64 * 36];

    const int tid = threadIdx.x;
    const int n0 = blockIdx.x * 64;

    for (int idx = tid; idx < FDIM * K; idx += 256) {
        int fr = idx / K;
        int kr = idx - fr * K;
        wt[kr * 65 + fr] = W[idx];
    }

    const int f = tid & 63;
    const int q = tid >> 6;
    float acc[16];
#pragma unroll
    for (int j = 0; j < 16; ++j) acc[j] = 0.f;

    for (int kc = 0; kc < K; kc += 32) {
        __syncthreads();   // protect xs from previous iteration's readers
#pragma unroll
        for (int u = tid; u < 512; u += 256) {
            int node = u >> 3;
            int k4 = u & 7;
            int gn = n0 + node;
            float4 a = make_float4(0.f, 0.f, 0.f, 0.f);
            if (gn < n) a = *reinterpret_cast<const float4*>(&A[(size_t)gn * K + kc + k4 * 4]);
            *reinterpret_cast<float4*>(&xs[node * 36 + k4 * 4]) = a;
        }
        __syncthreads();

#pragma unroll
        for (int kk = 0; kk < 32; kk += 4) {
            float w0 = wt[(kc + kk + 0) * 65 + f];
            float w1 = wt[(kc + kk + 1) * 65 + f];
            float w2 = wt[(kc + kk + 2) * 65 + f];
            float w3 = wt[(kc + kk + 3) * 65 + f];
#pragma unroll
            for (int jj = 0; jj < 16; ++jj) {
                int j = jj * 4 + q;
                float4 av = *reinterpret_cast<const float4*>(&xs[j * 36 + kk]);
                acc[jj] = fmaf(av.x, w0, fmaf(av.y, w1, fmaf(av.z, w2, fmaf(av.w, w3, acc[jj]))));
            }
        }
    }

#pragma unroll
    for (int jj = 0; jj < 16; ++jj) {
        int node = n0 + jj * 4 + q;
        if (node < n) out[(size_t)node * FDIM + f] = acc[jj];
    }
}

// ============ fused dgconv gather x3 + self-loop + bias + relu ============
// one 64-lane wave per node; lane = feature.

__global__ __launch_bounds__(256) void k_gather(const float* __restrict__ h,
                                                const float* __restrict__ dis,     // [3][N]
                                                const int* __restrict__ rowptr,    // [3][N+1]
                                                const int* __restrict__ src,       // [3][E]
                                                const float* __restrict__ val,     // [3][E]
                                                const float* __restrict__ bias,    // [64]
                                                float* __restrict__ cat,           // [N][192]
                                                int N, int E) {
    int i = blockIdx.x * 4 + (threadIdx.x >> 6);
    if (i >= N) return;
    const int lane = threadIdx.x & 63;

    const float hv = h[(size_t)i * FDIM + lane];
    const float b = bias[lane];

#pragma unroll
    for (int g = 0; g < 3; ++g) {
        const int* rp = rowptr + g * (N + 1);
        const int* sg = src + (size_t)g * E;
        const float* vg = val + (size_t)g * E;
        int beg = rp[i], end = rp[i + 1];
        float dg = dis[g * N + i];

        float acc0 = 0.f, acc1 = 0.f;
        for (int base = beg; base < end; base += 64) {
            int idx = base + lane;
            bool ok = idx < end;
            int s = ok ? sg[idx] : 0;
            float v = ok ? vg[idx] : 0.f;
            int m = end - base;
            if (m > 64) m = 64;
            int j = 0;
            for (; j + 1 < m; j += 2) {
                int s0 = __shfl(s, j);
                int s1 = __shfl(s, j + 1);
                float v0 = __shfl(v, j);
                float v1 = __shfl(v, j + 1);
                float a0 = h[(size_t)s0 * FDIM + lane];
                float a1 = h[(size_t)s1 * FDIM + lane];
                acc0 = fmaf(v0, a0, acc0);
                acc1 = fmaf(v1, a1, acc1);
            }
            if (j < m) {
                int s0 = __shfl(s, j);
                float v0 = __shfl(v, j);
                acc0 = fmaf(v0, h[(size_t)s0 * FDIM + lane], acc0);
            }
        }
        float outv = dg * (acc0 + acc1) + dg * dg * hv + b;
        cat[(size_t)i * CATDIM + g * FDIM + lane] = outv > 0.f ? outv : 0.f;
    }
}

// ============ head: pointwise conv (16 out) + log_softmax ============

__global__ __launch_bounds__(256) void k_final(const float* __restrict__ cat,
                                               const float* __restrict__ convw,  // [16][192]
                                               const float* __restrict__ convb,  // [16]
                                               float* __restrict__ out, int n) {
    __shared__ float wl[16 * 196];
    __shared__ float bl[16];
    const int tid = threadIdx.x;
    for (int t = tid; t < 16 * 192; t += 256) {
        int o = t / 192;
        int k = t - o * 192;
        wl[o * 196 + k] = convw[t];
    }
    if (tid < 16) bl[tid] = convb[tid];
    __syncthreads();

    const int o = tid & 15;
    const int node = blockIdx.x * 16 + (tid >> 4);
    const int nc = node < n ? node : n - 1;

    const float4* xr = reinterpret_cast<const float4*>(cat + (size_t)nc * CATDIM);
    const float* wr = &wl[o * 196];
    float acc = bl[o];
#pragma unroll
    for (int k4 = 0; k4 < CATDIM / 4; ++k4) {
        float4 xv = xr[k4];
        acc += xv.x * wr[k4 * 4 + 0] + xv.y * wr[k4 * 4 + 1] +
               xv.z * wr[k4 * 4 + 2] + xv.w * wr[k4 * 4 + 3];
    }

    float m = acc;
    m = fmaxf(m, __shfl_xor(m, 1));
    m = fmaxf(m, __shfl_xor(m, 2));
    m = fmaxf(m, __shfl_xor(m, 4));
    m = fmaxf(m, __shfl_xor(m, 8));
    float s = __expf(acc - m);
    s += __shfl_xor(s, 1);
    s += __shfl_xor(s, 2);
    s += __shfl_xor(s, 4);
    s += __shfl_xor(s, 8);
    if (node < n) out[(size_t)node * 16 + o] = acc - m - logf(s);
}

// ============ launch ============

extern "C" void kernel_launch(void* const* d_in, const int* in_sizes, int n_in,
                              void* d_out, int out_size, void* d_ws, size_t ws_size,
                              hipStream_t stream) {
    const float* x      = (const float*)d_in[0];
    const int*   ei     = (const int*)d_in[1];
    const int*   e_in   = (const int*)d_in[2];
    const int*   e_out  = (const int*)d_in[3];
    const float* in_w   = (const float*)d_in[4];
    const float* out_w  = (const float*)d_in[5];
    const float* lin1_w = (const float*)d_in[6];
    const float* lin2_w = (const float*)d_in[7];
    const float* bias1  = (const float*)d_in[8];
    const float* bias2  = (const float*)d_in[9];
    const float* conv_w = (const float*)d_in[10];
    const float* conv_b = (const float*)d_in[11];
    float* out = (float*)d_out;

    const int N = in_sizes[0] / 128;
    const int E = in_sizes[1] / 2;
    const int nblk = (N + 1 + 255) / 256;   // scan blocks per graph (covers index N)

    // workspace layout (floats / ints, 4B each)
    float* ws = (float*)d_ws;
    size_t o = 0;
    float* dis    = ws + o;            o += (size_t)3 * N;                 // deg then dis
    int*   rowptr = (int*)(ws + o);    o += ((size_t)3 * (N + 1) + 63) & ~63ull;
    int*   cursor = (int*)(ws + o);    o += ((size_t)3 * (N + 1) + 63) & ~63ull;
    int*   bsum   = (int*)(ws + o);    o += (size_t)3 * 256;
    float* h      = ws + o;            o += (size_t)N * FDIM;
    int*   src    = (int*)(ws + o);    o += (size_t)3 * E;
    float* val    = ws + o;            o += (size_t)3 * E;
    float* cat    = ws + o;            o += (size_t)N * CATDIM;
    int*   cnt    = (int*)cat;         // alias: cnt dead before cat first written

    const int B = 256;

    // normalization + CSR build
    hipLaunchKernelGGL(k_init, dim3((3 * N + B - 1) / B), dim3(B), 0, stream, dis, cnt, 3 * N);
    hipLaunchKernelGGL(k_edge_pass1, dim3((E + B - 1) / B), dim3(B), 0, stream,
                       ei, e_in, e_out, in_w, out_w, dis, cnt, N, E);
    hipLaunchKernelGGL(k_dis, dim3((3 * N + B - 1) / B), dim3(B), 0, stream, dis, 3 * N);
    hipLaunchKernelGGL(k_scan1, dim3(nblk, 3), dim3(B), 0, stream, cnt, bsum, N, nblk);
    hipLaunchKernelGGL(k_scan2, dim3(3), dim3(B), 0, stream, bsum, nblk);
    hipLaunchKernelGGL(k_scan3, dim3(nblk, 3), dim3(B), 0, stream, cnt, bsum, rowptr, cursor, N, nblk);
    hipLaunchKernelGGL(k_fill, dim3((E + B - 1) / B), dim3(B), 0, stream,
                       ei, e_in, e_out, in_w, out_w, dis, cursor, src, val, N, E);

    // layer 1
    hipLaunchKernelGGL((k_gemm<128>), dim3((N + 63) / 64), dim3(B), 0, stream, x, lin1_w, h, N);
    hipLaunchKernelGGL(k_gather, dim3((N + 3) / 4), dim3(B), 0, stream,
                       h, dis, rowptr, src, val, bias1, cat, N, E);

    // layer 2
    hipLaunchKernelGGL((k_gemm<192>), dim3((N + 63) / 64), dim3(B), 0, stream, cat, lin2_w, h, N);
    hipLaunchKernelGGL(k_gather, dim3((N + 3) / 4), dim3(B), 0, stream,
                       h, dis, rowptr, src, val, bias2, cat, N, E);

    // head
    hipLaunchKernelGGL(k_final, dim3((N + 15) / 16), dim3(B), 0, stream, cat, conv_w, conv_b, out, N);
}

// Round 3
// 724.997 us; speedup vs baseline: 2.1269x; 1.1236x over previous
//
#include <hip/hip_runtime.h>
#include <math.h>

#define FDIM 64
#define CATDIM 192

// ============ zero cnt ============

__global__ void k_zero(int* __restrict__ cnt, int n3) {
    int i = blockIdx.x * blockDim.x + threadIdx.x;
    if (i < n3) cnt[i] = 0;
}

// ============ edge pass 1: destination histogram only (3 int atomics/edge) ============

__global__ void k_hist(const int* __restrict__ ei0,
                       const int* __restrict__ ei1,
                       const int* __restrict__ ei2,
                       int* __restrict__ cnt,     // [3][N]
                       int N, int E) {
    int e = blockIdx.x * blockDim.x + threadIdx.x;
    if (e >= E) return;
    atomicAdd(&cnt[ei0[E + e]], 1);
    atomicAdd(&cnt[N + ei1[E + e]], 1);
    atomicAdd(&cnt[2 * N + ei2[E + e]], 1);
}

// ============ hierarchical exclusive scan of cnt -> rowptr, cursor ============

__global__ void k_scan1(const int* __restrict__ cnt, int* __restrict__ bsum,
                        int N, int nblk) {
    __shared__ int r[256];
    int g = blockIdx.y, b = blockIdx.x, tid = threadIdx.x;
    int i = b * 256 + tid;
    int v = (i < N) ? cnt[g * N + i] : 0;
    r[tid] = v;
    __syncthreads();
    for (int d = 128; d > 0; d >>= 1) {
        if (tid < d) r[tid] += r[tid + d];
        __syncthreads();
    }
    if (tid == 0) bsum[g * nblk + b] = r[0];
}

__global__ void k_scan2(int* bsum, int nblk) {
    __shared__ int s[256];
    int g = blockIdx.x, tid = threadIdx.x;
    int v = (tid < nblk) ? bsum[g * nblk + tid] : 0;
    s[tid] = v;
    __syncthreads();
    for (int d = 1; d < 256; d <<= 1) {
        int t = (tid >= d) ? s[tid - d] : 0;
        __syncthreads();
        s[tid] += t;
        __syncthreads();
    }
    if (tid < nblk) bsum[g * nblk + tid] = s[tid] - v;   // exclusive
}

__global__ void k_scan3(const int* __restrict__ cnt, const int* __restrict__ bsum,
                        int* __restrict__ rowptr, int* __restrict__ cursor,
                        int N, int nblk) {
    __shared__ int s[256];
    int g = blockIdx.y, b = blockIdx.x, tid = threadIdx.x;
    int i = b * 256 + tid;
    int v = (i < N) ? cnt[g * N + i] : 0;
    s[tid] = v;
    __syncthreads();
    for (int d = 1; d < 256; d <<= 1) {
        int t = (tid >= d) ? s[tid - d] : 0;
        __syncthreads();
        s[tid] += t;
        __syncthreads();
    }
    if (i <= N) {
        int e = bsum[g * nblk + b] + (s[tid] - v);
        rowptr[g * (N + 1) + i] = e;
        cursor[g * (N + 1) + i] = e;
    }
}

// ============ edge pass 2: fill CSR (src node + raw weight) ============
// graph 0 has w==1 so val is not written (k_scale overwrites it with dis[src]).

__global__ void k_fill(const int* __restrict__ ei0,
                       const int* __restrict__ ei1,
                       const int* __restrict__ ei2,
                       const float* __restrict__ w1,
                       const float* __restrict__ w2,
                       int* __restrict__ cursor,        // [3][N+1]
                       int* __restrict__ src,           // [3][E]
                       float* __restrict__ val,         // [3][E]
                       int N, int E) {
    int e = blockIdx.x * blockDim.x + threadIdx.x;
    if (e >= E) return;
    {
        int r = ei0[e], c = ei0[E + e];
        int slot = atomicAdd(&cursor[c], 1);
        src[slot] = r;
    }
    {
        int r = ei1[e], c = ei1[E + e];
        int slot = atomicAdd(&cursor[(N + 1) + c], 1);
        src[E + slot] = r;
        val[E + slot] = w1[e];
    }
    {
        int r = ei2[e], c = ei2[E + e];
        int slot = atomicAdd(&cursor[2 * (N + 1) + c], 1);
        src[2 * E + slot] = r;
        val[2 * E + slot] = w2[e];
    }
}

// ============ degree from CSR row sums -> dis = rsqrt(1 + sum w) ============

__global__ void k_degdis(const int* __restrict__ rowptr,   // [3][N+1]
                         const float* __restrict__ val,    // [3][E]
                         float* __restrict__ dis,          // [3][N]
                         int N, int E) {
    int i = blockIdx.x * blockDim.x + threadIdx.x;
    int g = blockIdx.y;
    if (i >= N) return;
    const int* rp = rowptr + g * (N + 1);
    int beg = rp[i], end = rp[i + 1];
    float s = 1.0f;                      // self-loop weight
    if (g == 0) {
        s += (float)(end - beg);         // all weights are 1
    } else {
        const float* vg = val + (size_t)g * E;
        for (int j = beg; j < end; ++j) s += vg[j];
    }
    dis[g * N + i] = rsqrtf(s);          // s >= 1, no zero guard needed
}

// ============ premultiply val by dis[src] ============

__global__ void k_scale(const int* __restrict__ src, float* __restrict__ val,
                        const float* __restrict__ dis, int N, int E) {
    int idx = blockIdx.x * blockDim.x + threadIdx.x;
    if (idx >= 3 * E) return;
    int g = idx >= 2 * E ? 2 : (idx >= E ? 1 : 0);
    float d = dis[g * N + src[idx]];
    val[idx] = (g == 0) ? d : val[idx] * d;
}

// ============ GEMM: out[n][64] = A[n][K] * W[64][K]^T ============

template <int K>
__global__ __launch_bounds__(256) void k_gemm(const float* __restrict__ A,
                                              const float* __restrict__ W,
                                              float* __restrict__ out, int n) {
    __shared__ float wt[K * 65];
    __shared__ float xs[64 * 36];

    const int tid = threadIdx.x;
    const int n0 = blockIdx.x * 64;

    for (int idx = tid; idx < FDIM * K; idx += 256) {
        int fr = idx / K;
        int kr = idx - fr * K;
        wt[kr * 65 + fr] = W[idx];
    }

    const int f = tid & 63;
    const int q = tid >> 6;
    float acc[16];
#pragma unroll
    for (int j = 0; j < 16; ++j) acc[j] = 0.f;

    for (int kc = 0; kc < K; kc += 32) {
        __syncthreads();
#pragma unroll
        for (int u = tid; u < 512; u += 256) {
            int node = u >> 3;
            int k4 = u & 7;
            int gn = n0 + node;
            float4 a = make_float4(0.f, 0.f, 0.f, 0.f);
            if (gn < n) a = *reinterpret_cast<const float4*>(&A[(size_t)gn * K + kc + k4 * 4]);
            *reinterpret_cast<float4*>(&xs[node * 36 + k4 * 4]) = a;
        }
        __syncthreads();

#pragma unroll
        for (int kk = 0; kk < 32; kk += 4) {
            float w0 = wt[(kc + kk + 0) * 65 + f];
            float w1 = wt[(kc + kk + 1) * 65 + f];
            float w2 = wt[(kc + kk + 2) * 65 + f];
            float w3 = wt[(kc + kk + 3) * 65 + f];
#pragma unroll
            for (int jj = 0; jj < 16; ++jj) {
                int j = jj * 4 + q;
                float4 av = *reinterpret_cast<const float4*>(&xs[j * 36 + kk]);
                acc[jj] = fmaf(av.x, w0, fmaf(av.y, w1, fmaf(av.z, w2, fmaf(av.w, w3, acc[jj]))));
            }
        }
    }

#pragma unroll
    for (int jj = 0; jj < 16; ++jj) {
        int node = n0 + jj * 4 + q;
        if (node < n) out[(size_t)node * FDIM + f] = acc[jj];
    }
}

// ============ fused dgconv gather x3 + self-loop + bias + relu ============
// one 64-lane wave per node; lane = feature. 4-way ILP on the row loop.

__global__ __launch_bounds__(256) void k_gather(const float* __restrict__ h,
                                                const float* __restrict__ dis,     // [3][N]
                                                const int* __restrict__ rowptr,    // [3][N+1]
                                                const int* __restrict__ src,       // [3][E]
                                                const float* __restrict__ val,     // [3][E]
                                                const float* __restrict__ bias,    // [64]
                                                float* __restrict__ cat,           // [N][192]
                                                int N, int E) {
    int i = blockIdx.x * 4 + (threadIdx.x >> 6);
    if (i >= N) return;
    const int lane = threadIdx.x & 63;

    const float hv = h[(size_t)i * FDIM + lane];
    const float b = bias[lane];

#pragma unroll
    for (int g = 0; g < 3; ++g) {
        const int* rp = rowptr + g * (N + 1);
        const int* sg = src + (size_t)g * E;
        const float* vg = val + (size_t)g * E;
        int beg = rp[i], end = rp[i + 1];
        float dg = dis[g * N + i];

        float acc0 = 0.f, acc1 = 0.f, acc2 = 0.f, acc3 = 0.f;
        for (int base = beg; base < end; base += 64) {
            int idx = base + lane;
            bool ok = idx < end;
            int s = ok ? sg[idx] : 0;
            float v = ok ? vg[idx] : 0.f;
            int m = end - base;
            if (m > 64) m = 64;
            int j = 0;
            for (; j + 3 < m; j += 4) {
                int s0 = __shfl(s, j);
                int s1 = __shfl(s, j + 1);
                int s2 = __shfl(s, j + 2);
                int s3 = __shfl(s, j + 3);
                float v0 = __shfl(v, j);
                float v1 = __shfl(v, j + 1);
                float v2 = __shfl(v, j + 2);
                float v3 = __shfl(v, j + 3);
                float a0 = h[(size_t)s0 * FDIM + lane];
                float a1 = h[(size_t)s1 * FDIM + lane];
                float a2 = h[(size_t)s2 * FDIM + lane];
                float a3 = h[(size_t)s3 * FDIM + lane];
                acc0 = fmaf(v0, a0, acc0);
                acc1 = fmaf(v1, a1, acc1);
                acc2 = fmaf(v2, a2, acc2);
                acc3 = fmaf(v3, a3, acc3);
            }
            for (; j < m; ++j) {
                int s0 = __shfl(s, j);
                float v0 = __shfl(v, j);
                acc0 = fmaf(v0, h[(size_t)s0 * FDIM + lane], acc0);
            }
        }
        float outv = dg * ((acc0 + acc1) + (acc2 + acc3)) + dg * dg * hv + b;
        cat[(size_t)i * CATDIM + g * FDIM + lane] = outv > 0.f ? outv : 0.f;
    }
}

// ============ head: pointwise conv (16 out) + log_softmax ============

__global__ __launch_bounds__(256) void k_final(const float* __restrict__ cat,
                                               const float* __restrict__ convw,  // [16][192]
                                               const float* __restrict__ convb,  // [16]
                                               float* __restrict__ out, int n) {
    __shared__ float wl[16 * 196];
    __shared__ float bl[16];
    const int tid = threadIdx.x;
    for (int t = tid; t < 16 * 192; t += 256) {
        int o = t / 192;
        int k = t - o * 192;
        wl[o * 196 + k] = convw[t];
    }
    if (tid < 16) bl[tid] = convb[tid];
    __syncthreads();

    const int o = tid & 15;
    const int node = blockIdx.x * 16 + (tid >> 4);
    const int nc = node < n ? node : n - 1;

    const float4* xr = reinterpret_cast<const float4*>(cat + (size_t)nc * CATDIM);
    const float* wr = &wl[o * 196];
    float acc = bl[o];
#pragma unroll
    for (int k4 = 0; k4 < CATDIM / 4; ++k4) {
        float4 xv = xr[k4];
        acc += xv.x * wr[k4 * 4 + 0] + xv.y * wr[k4 * 4 + 1] +
               xv.z * wr[k4 * 4 + 2] + xv.w * wr[k4 * 4 + 3];
    }

    float m = acc;
    m = fmaxf(m, __shfl_xor(m, 1));
    m = fmaxf(m, __shfl_xor(m, 2));
    m = fmaxf(m, __shfl_xor(m, 4));
    m = fmaxf(m, __shfl_xor(m, 8));
    float s = __expf(acc - m);
    s += __shfl_xor(s, 1);
    s += __shfl_xor(s, 2);
    s += __shfl_xor(s, 4);
    s += __shfl_xor(s, 8);
    if (node < n) out[(size_t)node * 16 + o] = acc - m - logf(s);
}

// ============ launch ============

extern "C" void kernel_launch(void* const* d_in, const int* in_sizes, int n_in,
                              void* d_out, int out_size, void* d_ws, size_t ws_size,
                              hipStream_t stream) {
    const float* x      = (const float*)d_in[0];
    const int*   ei     = (const int*)d_in[1];
    const int*   e_in   = (const int*)d_in[2];
    const int*   e_out  = (const int*)d_in[3];
    const float* in_w   = (const float*)d_in[4];
    const float* out_w  = (const float*)d_in[5];
    const float* lin1_w = (const float*)d_in[6];
    const float* lin2_w = (const float*)d_in[7];
    const float* bias1  = (const float*)d_in[8];
    const float* bias2  = (const float*)d_in[9];
    const float* conv_w = (const float*)d_in[10];
    const float* conv_b = (const float*)d_in[11];
    float* out = (float*)d_out;

    const int N = in_sizes[0] / 128;
    const int E = in_sizes[1] / 2;
    const int nblk = (N + 1 + 255) / 256;

    // workspace layout
    float* ws = (float*)d_ws;
    size_t o = 0;
    float* dis    = ws + o;            o += (size_t)3 * N;
    int*   rowptr = (int*)(ws + o);    o += ((size_t)3 * (N + 1) + 63) & ~63ull;
    int*   cursor = (int*)(ws + o);    o += ((size_t)3 * (N + 1) + 63) & ~63ull;
    int*   bsum   = (int*)(ws + o);    o += (size_t)3 * 256;
    float* h      = ws + o;            o += (size_t)N * FDIM;
    int*   src    = (int*)(ws + o);    o += (size_t)3 * E;
    float* val    = ws + o;            o += (size_t)3 * E;
    float* cat    = ws + o;            o += (size_t)N * CATDIM;
    int*   cnt    = (int*)cat;         // alias: cnt dead before cat first written

    const int B = 256;

    // CSR build + normalization
    hipLaunchKernelGGL(k_zero, dim3((3 * N + B - 1) / B), dim3(B), 0, stream, cnt, 3 * N);
    hipLaunchKernelGGL(k_hist, dim3((E + B - 1) / B), dim3(B), 0, stream, ei, e_in, e_out, cnt, N, E);
    hipLaunchKernelGGL(k_scan1, dim3(nblk, 3), dim3(B), 0, stream, cnt, bsum, N, nblk);
    hipLaunchKernelGGL(k_scan2, dim3(3), dim3(B), 0, stream, bsum, nblk);
    hipLaunchKernelGGL(k_scan3, dim3(nblk, 3), dim3(B), 0, stream, cnt, bsum, rowptr, cursor, N, nblk);
    hipLaunchKernelGGL(k_fill, dim3((E + B - 1) / B), dim3(B), 0, stream,
                       ei, e_in, e_out, in_w, out_w, cursor, src, val, N, E);
    hipLaunchKernelGGL(k_degdis, dim3((N + B - 1) / B, 3), dim3(B), 0, stream, rowptr, val, dis, N, E);
    hipLaunchKernelGGL(k_scale, dim3((3 * E + B - 1) / B), dim3(B), 0, stream, src, val, dis, N, E);

    // layer 1
    hipLaunchKernelGGL((k_gemm<128>), dim3((N + 63) / 64), dim3(B), 0, stream, x, lin1_w, h, N);
    hipLaunchKernelGGL(k_gather, dim3((N + 3) / 4), dim3(B), 0, stream,
                       h, dis, rowptr, src, val, bias1, cat, N, E);

    // layer 2
    hipLaunchKernelGGL((k_gemm<192>), dim3((N + 63) / 64), dim3(B), 0, stream, cat, lin2_w, h, N);
    hipLaunchKernelGGL(k_gather, dim3((N + 3) / 4), dim3(B), 0, stream,
                       h, dis, rowptr, src, val, bias2, cat, N, E);

    // head
    hipLaunchKernelGGL(k_final, dim3((N + 15) / 16), dim3(B), 0, stream, cat, conv_w, conv_b, out, N);
}